// Round 5
// baseline (19798.927 us; speedup 1.0000x reference)
//
#include <hip/hip_runtime.h>
#include <hip/hip_bf16.h>

// ============================================================================
// BilateralGenerator: 3-layer coupled LSTM, B=128 T=512 H=512 ND=128 LD=128.
//
// Round 5: r4's cross-wave LDS partial exchange + dynamic acc[] register
// indexing produced 0.088 error (codegen/exchange hazard). This round keeps
// register blocking but with FULLY INDEPENDENT waves, math identical to the
// r2-passing kernel:
//  - Wave tile [32 rows x 64 gcols], acc[2][4] (all indices compile-time).
//    Each wave does the FULL K: x-path then h-path accumulated sequentially
//    into one fp32 accumulator (r2's exact pattern). No LDS, no barriers.
//  - 384 cell waves (3 layers x 4 rowgroups x 32 colgroups) + 8 out-proj
//    waves = 196 blocks x 128 threads per tick. B frags reused 2x from regs.
//  - 515 tick launches (proven structure); split-precision bf16 hi/lo GEMMs.
// ============================================================================

typedef unsigned short ushort_t;

using frag_ab = __attribute__((ext_vector_type(8))) short;  // 8 bf16
using frag_cd = __attribute__((ext_vector_type(4))) float;  // 4 fp32

#define B_   128
#define T_   512
#define ND_  128
#define H_   512
#define G_   2048   // 4*H
#define LD_  128

// ---- workspace layout (ushort element offsets into bf16 region) ----
#define OFF_WHH   0u          // Wh hi: 3 x 512*2048
#define OFF_WHL   3145728u    // Wh lo
#define OFF_WXH   6291456u    // Wx hi: Wx0 (128*2048) then Wxr[0], Wxr[1]
#define OFF_WXL   8650752u    // Wx lo
#define OFF_WCH   11010048u   // Wc hi: 3 x 512*2048
#define OFF_WCL   14155776u   // Wc lo
#define OFF_WOUT  17301504u   // Wout hi: 512*128
#define OFF_HCH   17367040u   // h_coupled hi: 3 x 128*512
#define OFF_HCL   17563648u   // h_coupled lo
#define OFF_HBH   17760256u   // h buf hi: 3 layers x 2 parity x 128*512
#define OFF_HBL   18153472u   // h buf lo
#define OFF_SCR   18546688u   // scratch (Wout lo, unused): 65536
#define USH_BYTES 37224448u   // 18612224 ushorts * 2
// ---- fp32 region (float element offsets from USH_BYTES) ----
#define FOFF_C     0u         // c state: 3 x 128*512
#define FOFF_CTERM 196608u    // Cterm: 3 x 128*2048

__device__ inline float sig_(float x)  { return 1.0f / (1.0f + __expf(-x)); }
__device__ inline float tanh_(float x) { return 2.0f / (1.0f + __expf(-2.0f * x)) - 1.0f; }

__device__ inline ushort_t f2b(float f) {
    __hip_bfloat16 h = __float2bfloat16(f);           // RNE
    return __builtin_bit_cast(unsigned short, h);
}
__device__ inline float b2f(ushort_t u) {
    unsigned int v = ((unsigned int)u) << 16;
    return __builtin_bit_cast(float, v);
}

// ---------------------------------------------------------------------------
// Weight swizzle + hi/lo split (round-2 verified).
// ---------------------------------------------------------------------------
__global__ void swz_kernel(const float* __restrict__ src,
                           ushort_t* __restrict__ dhi, ushort_t* __restrict__ dlo,
                           int K, int N) {
    int tid = blockIdx.x * 256 + threadIdx.x;
    int total = (K >> 5) * (N >> 4) * 64;
    if (tid >= total) return;
    int lane = tid & 63;
    int rest = tid >> 6;
    int NF = N >> 4;
    int nf = rest % NF;
    int kb = rest / NF;
    int kbase = kb * 32 + (lane >> 4) * 8;
    int n = nf * 16 + (lane & 15);
    union { ushort_t u[8]; uint4 v; } thi, tlo;
#pragma unroll
    for (int j = 0; j < 8; ++j) {
        float v = src[(size_t)(kbase + j) * N + n];
        ushort_t hi = f2b(v);
        thi.u[j] = hi;
        tlo.u[j] = f2b(v - b2f(hi));
    }
    *(uint4*)(dhi + (size_t)tid * 8) = thi.v;
    *(uint4*)(dlo + (size_t)tid * 8) = tlo.v;
}

__global__ void cvt_kernel(const float* __restrict__ src,
                           ushort_t* __restrict__ dhi, ushort_t* __restrict__ dlo, int n) {
    int i = blockIdx.x * 256 + threadIdx.x;
    if (i >= n) return;
    float v = src[i];
    ushort_t hi = f2b(v);
    dhi[i] = hi;
    dlo[i] = f2b(v - b2f(hi));
}

// ---------------------------------------------------------------------------
// Split-precision [16x64]-per-wave GEMM (round-2 verified) for cterm only.
// ---------------------------------------------------------------------------
__device__ inline void mfma_seg3(const ushort_t* __restrict__ Ah,
                                 const ushort_t* __restrict__ Al,
                                 const ushort_t* __restrict__ Bh,
                                 const ushort_t* __restrict__ Bl,
                                 int rowA, int cg, int nkb, frag_cd acc[4]) {
    int lane = threadIdx.x & 63;
    int koff = (lane >> 4) * 8;
#pragma unroll 2
    for (int kb = 0; kb < nkb; ++kb) {
        frag_ab ah = *(const frag_ab*)(Ah + (size_t)rowA * H_ + kb * 32 + koff);
        frag_ab al = *(const frag_ab*)(Al + (size_t)rowA * H_ + kb * 32 + koff);
#pragma unroll
        for (int q = 0; q < 4; ++q) {
            size_t bo = ((size_t)(kb * 128 + q * 32 + cg) * 64 + lane) * 8;
            frag_ab bh = *(const frag_ab*)(Bh + bo);
            frag_ab bl = *(const frag_ab*)(Bl + bo);
            acc[q] = __builtin_amdgcn_mfma_f32_16x16x32_bf16(ah, bh, acc[q], 0, 0, 0);
            acc[q] = __builtin_amdgcn_mfma_f32_16x16x32_bf16(ah, bl, acc[q], 0, 0, 0);
            acc[q] = __builtin_amdgcn_mfma_f32_16x16x32_bf16(al, bh, acc[q], 0, 0, 0);
        }
    }
}

__global__ __launch_bounds__(256) void cterm_kernel(char* __restrict__ ws,
                                                    const float* __restrict__ bias) {
    ushort_t* wsU = (ushort_t*)ws;
    float* wsF = (float*)(ws + USH_BYTES);
    int lane = threadIdx.x & 63, w = threadIdx.x >> 6;
    int bid = blockIdx.x;
    int layer = bid >> 6;
    int sub = bid & 63;
    int rg = sub >> 5, cg = sub & 31;
    int m = lane & 15, kq = lane >> 4;
    int r0 = rg * 64 + w * 16;
    int rowA = r0 + m;
    frag_cd acc[4] = {};
    mfma_seg3(wsU + OFF_HCH + layer * 65536, wsU + OFF_HCL + layer * 65536,
              wsU + OFF_WCH + (size_t)layer * 1048576, wsU + OFF_WCL + (size_t)layer * 1048576,
              rowA, cg, 16, acc);
    float* ct = wsF + FOFF_CTERM + (size_t)layer * 262144;
#pragma unroll
    for (int reg = 0; reg < 4; ++reg) {
        int row = r0 + kq * 4 + reg;
#pragma unroll
        for (int q = 0; q < 4; ++q) {
            int gcol = q * 512 + cg * 16 + m;
            ct[(size_t)row * G_ + gcol] = acc[q][reg] + bias[layer * G_ + gcol];
        }
    }
}

// ---------------------------------------------------------------------------
// Split-precision [32 rows x 64 gcols]-per-wave segment: 2 rowtiles,
// B frags reused 2x from registers. All acc indices compile-time.
// ---------------------------------------------------------------------------
__device__ inline void seg_accum32(const ushort_t* __restrict__ Ah,
                                   const ushort_t* __restrict__ Al,
                                   const ushort_t* __restrict__ Bh,
                                   const ushort_t* __restrict__ Bl,
                                   int r0, int cg, int nkb, frag_cd acc[2][4]) {
    int lane = threadIdx.x & 63;
    int m = lane & 15;
    int koff = (lane >> 4) * 8;
#pragma unroll 2
    for (int kb = 0; kb < nkb; ++kb) {
        frag_ab ah[2], al[2];
#pragma unroll
        for (int rt = 0; rt < 2; ++rt) {
            size_t ao = (size_t)(r0 + rt * 16 + m) * H_ + kb * 32 + koff;
            ah[rt] = *(const frag_ab*)(Ah + ao);
            al[rt] = *(const frag_ab*)(Al + ao);
        }
#pragma unroll
        for (int q = 0; q < 4; ++q) {
            size_t bo = ((size_t)(kb * 128 + q * 32 + cg) * 64 + lane) * 8;
            frag_ab bh = *(const frag_ab*)(Bh + bo);
            frag_ab bl = *(const frag_ab*)(Bl + bo);
#pragma unroll
            for (int rt = 0; rt < 2; ++rt) {
                acc[rt][q] = __builtin_amdgcn_mfma_f32_16x16x32_bf16(ah[rt], bh, acc[rt][q], 0, 0, 0);
                acc[rt][q] = __builtin_amdgcn_mfma_f32_16x16x32_bf16(ah[rt], bl, acc[rt][q], 0, 0, 0);
                acc[rt][q] = __builtin_amdgcn_mfma_f32_16x16x32_bf16(al[rt], bh, acc[rt][q], 0, 0, 0);
            }
        }
    }
}

// ---------------------------------------------------------------------------
// One pipeline tick: 196 blocks x 128 threads = 392 independent waves.
// wid = bid*2 + w. wid < 384: cell waves (layer = wid/128, rg = 0..3 row
// groups of 32, cg = 0..31), full K (x-path + h-path) per wave.
// wid >= 384: out-proj waves (4 rowgroups x 2 col halves).
// ---------------------------------------------------------------------------
__global__ __launch_bounds__(128) void tick_kernel(const float* __restrict__ noise,
                                                   char* __restrict__ ws,
                                                   float* __restrict__ out,
                                                   const float* __restrict__ bout,
                                                   int tick) {
    ushort_t* wsU = (ushort_t*)ws;
    float* wsF = (float*)(ws + USH_BYTES);
    int lane = threadIdx.x & 63;
    int w = threadIdx.x >> 6;
    int wid = blockIdx.x * 2 + w;
    int m = lane & 15, kq = lane >> 4;
    int koff = kq * 8;

    if (wid < 384) {
        int layer = wid >> 7;
        int sub = wid & 127;
        int rg = sub >> 5;          // 0..3 rowgroups of 32
        int cg = sub & 31;
        int s = tick - layer;
        if (s < 0 || s >= T_) return;
        int r0 = rg * 32;
        int hc = cg * 16 + m;
        frag_cd acc[2][4] = {};

        // ---- x-path: layer0 from noise (K=128, split on the fly), else
        //      h_{l-1} step s (K=512, hi/lo pair)
        if (layer == 0) {
            const ushort_t* Bh = wsU + OFF_WXH;
            const ushort_t* Bl = wsU + OFF_WXL;
#pragma unroll
            for (int kb = 0; kb < 4; ++kb) {
                frag_ab ah[2], al[2];
#pragma unroll
                for (int rt = 0; rt < 2; ++rt) {
                    const float* np = noise +
                        ((size_t)(r0 + rt * 16 + m) * T_ + s) * ND_ + kb * 32 + koff;
                    float4 f0 = *(const float4*)np;
                    float4 f1 = *(const float4*)(np + 4);
                    float xf[8] = {f0.x, f0.y, f0.z, f0.w, f1.x, f1.y, f1.z, f1.w};
#pragma unroll
                    for (int j = 0; j < 8; ++j) {
                        ushort_t hi = f2b(xf[j]);
                        ah[rt][j] = (short)hi;
                        al[rt][j] = (short)f2b(xf[j] - b2f(hi));
                    }
                }
#pragma unroll
                for (int q = 0; q < 4; ++q) {
                    size_t bo = ((size_t)(kb * 128 + q * 32 + cg) * 64 + lane) * 8;
                    frag_ab bh = *(const frag_ab*)(Bh + bo);
                    frag_ab bl = *(const frag_ab*)(Bl + bo);
#pragma unroll
                    for (int rt = 0; rt < 2; ++rt) {
                        acc[rt][q] = __builtin_amdgcn_mfma_f32_16x16x32_bf16(ah[rt], bh, acc[rt][q], 0, 0, 0);
                        acc[rt][q] = __builtin_amdgcn_mfma_f32_16x16x32_bf16(ah[rt], bl, acc[rt][q], 0, 0, 0);
                        acc[rt][q] = __builtin_amdgcn_mfma_f32_16x16x32_bf16(al[rt], bh, acc[rt][q], 0, 0, 0);
                    }
                }
            }
        } else {
            unsigned hb = (unsigned)((layer - 1) * 2 + (s & 1)) * 65536u;
            seg_accum32(wsU + OFF_HBH + hb, wsU + OFF_HBL + hb,
                        wsU + OFF_WXH + 262144u + (size_t)(layer - 1) * 1048576,
                        wsU + OFF_WXL + 262144u + (size_t)(layer - 1) * 1048576,
                        r0, cg, 16, acc);
        }
        // ---- h-path: h_l step s-1 (skip at s==0: h0 = 0), same accumulator
        if (s > 0) {
            unsigned hb = (unsigned)(layer * 2 + ((s - 1) & 1)) * 65536u;
            seg_accum32(wsU + OFF_HBH + hb, wsU + OFF_HBL + hb,
                        wsU + OFF_WHH + (size_t)layer * 1048576,
                        wsU + OFF_WHL + (size_t)layer * 1048576,
                        r0, cg, 16, acc);
        }

        // ---- activation epilogue: i,f,g,o in this lane's acc[rt][0..3]
        const float* ct = wsF + FOFF_CTERM + (size_t)layer * 262144;
        float* cst = wsF + FOFF_C + layer * 65536;
        ushort_t* hhi = wsU + OFF_HBH + (layer * 2 + (s & 1)) * 65536;
        ushort_t* hlo = wsU + OFF_HBL + (layer * 2 + (s & 1)) * 65536;
#pragma unroll
        for (int rt = 0; rt < 2; ++rt) {
#pragma unroll
            for (int reg = 0; reg < 4; ++reg) {
                int row = r0 + rt * 16 + kq * 4 + reg;
                const float* cr = ct + (size_t)row * G_ + hc;
                float gi = acc[rt][0][reg] + cr[0];
                float gf = acc[rt][1][reg] + cr[512];
                float gg = acc[rt][2][reg] + cr[1024];
                float go = acc[rt][3][reg] + cr[1536];
                float cp = (s > 0) ? cst[row * H_ + hc] : 0.0f;
                float cn = sig_(gf) * cp + sig_(gi) * tanh_(gg);
                float hn = sig_(go) * tanh_(cn);
                cst[row * H_ + hc] = cn;
                ushort_t hi = f2b(hn);
                hhi[row * H_ + hc] = hi;
                hlo[row * H_ + hc] = f2b(hn - b2f(hi));
                if (s == T_ - 1)   // h_fin, fp32, no bf16 quantization
                    out[8388608u + (size_t)layer * 65536 + row * H_ + hc] = hn;
            }
        }
    } else {
        // ---- output projection: out[:, sp, :] = sigmoid(h2[sp] @ Wout + bout)
        int sp = tick - 3;
        if (sp < 0 || sp >= T_) return;
        int owid = wid - 384;       // 0..7
        int rg = owid >> 1;         // 4 rowgroups of 32
        int ch = owid & 1;          // 2 col halves of 64
        int r0o = rg * 32;
        const ushort_t* A  = wsU + OFF_HBH + (4 + (sp & 1)) * 65536;
        const ushort_t* Bw = wsU + OFF_WOUT;
        frag_cd acc[2][4] = {};
#pragma unroll 2
        for (int kb = 0; kb < 16; ++kb) {
            frag_ab a[2];
#pragma unroll
            for (int rt = 0; rt < 2; ++rt)
                a[rt] = *(const frag_ab*)(A + (size_t)(r0o + rt * 16 + m) * H_ + kb * 32 + koff);
#pragma unroll
            for (int cf = 0; cf < 4; ++cf) {
                frag_ab b = *(const frag_ab*)(Bw + ((size_t)(kb * 8 + ch * 4 + cf) * 64 + lane) * 8);
#pragma unroll
                for (int rt = 0; rt < 2; ++rt)
                    acc[rt][cf] = __builtin_amdgcn_mfma_f32_16x16x32_bf16(a[rt], b, acc[rt][cf], 0, 0, 0);
            }
        }
#pragma unroll
        for (int rt = 0; rt < 2; ++rt)
#pragma unroll
            for (int cf = 0; cf < 4; ++cf)
#pragma unroll
                for (int reg = 0; reg < 4; ++reg) {
                    int row = r0o + rt * 16 + kq * 4 + reg;
                    int oc = ch * 64 + cf * 16 + m;
                    out[((size_t)row * T_ + sp) * LD_ + oc] =
                        sig_(acc[rt][cf][reg] + bout[oc]);
                }
    }
}

extern "C" void kernel_launch(void* const* d_in, const int* in_sizes, int n_in,
                              void* d_out, int out_size, void* d_ws, size_t ws_size,
                              hipStream_t stream) {
    const float* noise = (const float*)d_in[0];
    const float* hcpl  = (const float*)d_in[1];
    const float* Wx0   = (const float*)d_in[2];
    const float* Wxr   = (const float*)d_in[3];
    const float* Wh    = (const float*)d_in[4];
    const float* Wc    = (const float*)d_in[5];
    const float* bias  = (const float*)d_in[6];
    const float* Wout  = (const float*)d_in[7];
    const float* bout  = (const float*)d_in[8];
    float* out = (float*)d_out;
    char* ws = (char*)d_ws;
    ushort_t* wsU = (ushort_t*)ws;

    auto launch_swz = [&](const float* src, unsigned ohi, unsigned olo, int K, int N) {
        int total = (K / 32) * (N / 16) * 64;
        swz_kernel<<<(total + 255) / 256, 256, 0, stream>>>(src, wsU + ohi, wsU + olo, K, N);
    };
    for (int l = 0; l < 3; ++l)
        launch_swz(Wh + (size_t)l * H_ * G_, OFF_WHH + l * 1048576u, OFF_WHL + l * 1048576u, H_, G_);
    launch_swz(Wx0, OFF_WXH, OFF_WXL, ND_, G_);
    for (int l = 0; l < 2; ++l)
        launch_swz(Wxr + (size_t)l * H_ * G_, OFF_WXH + 262144u + l * 1048576u,
                   OFF_WXL + 262144u + l * 1048576u, H_, G_);
    for (int l = 0; l < 3; ++l)
        launch_swz(Wc + (size_t)l * H_ * G_, OFF_WCH + l * 1048576u, OFF_WCL + l * 1048576u, H_, G_);
    launch_swz(Wout, OFF_WOUT, OFF_SCR, H_, LD_);
    cvt_kernel<<<(3 * B_ * H_ + 255) / 256, 256, 0, stream>>>(hcpl, wsU + OFF_HCH, wsU + OFF_HCL,
                                                              3 * B_ * H_);
    cterm_kernel<<<192, 256, 0, stream>>>(ws, bias);

    // 515 ticks: layer l covers steps at ticks [l, l+511]; out-proj at [3, 514]
    for (int t = 0; t < 515; ++t)
        tick_kernel<<<196, 128, 0, stream>>>(noise, ws, out, bout, t);
}

// Round 6
// 8513.261 us; speedup vs baseline: 2.3257x; 2.3257x over previous
//
#include <hip/hip_runtime.h>
#include <hip/hip_bf16.h>

// ============================================================================
// BilateralGenerator: 3-layer coupled LSTM, B=128 T=512 H=512 ND=128 LD=128.
//
// Round 6: r5 passed (absmax .0039) but 19.8ms -> LATENCY-bound: 392 waves =
// ~1.5/CU, no overlap (r2 with 784 waves was 1.64x faster). This round:
//  - K-SPLIT waves: block = 4 waves computing ONE [64r x 64gc] tile, each
//    wave a K-quarter into its own acc[4][4] (static reg indices only);
//    partials summed via 64KB LDS exchange + one __syncthreads.
//  - 192 cell blocks + 2 out-proj blocks, 256 thr: 776 waves, all CUs busy,
//    B frags reused 4x in-register -> 48 MB/tick B traffic.
//  - XCD pinning: bid = rowgroup*96 + (layer*32+cg); 96%8==0 so both
//    rowgroups of a column tile hit XCD u%8 -> ~3MB weight slice per XCD
//    stays L2-resident across all 515 tick launches.
// Math identical to r2/r5 (split-precision bf16 hi/lo GEMMs).
// ============================================================================

typedef unsigned short ushort_t;

using frag_ab = __attribute__((ext_vector_type(8))) short;  // 8 bf16
using frag_cd = __attribute__((ext_vector_type(4))) float;  // 4 fp32

#define B_   128
#define T_   512
#define ND_  128
#define H_   512
#define G_   2048   // 4*H
#define LD_  128

// ---- workspace layout (ushort element offsets into bf16 region) ----
#define OFF_WHH   0u          // Wh hi: 3 x 512*2048
#define OFF_WHL   3145728u    // Wh lo
#define OFF_WXH   6291456u    // Wx hi: Wx0 (128*2048) then Wxr[0], Wxr[1]
#define OFF_WXL   8650752u    // Wx lo
#define OFF_WCH   11010048u   // Wc hi: 3 x 512*2048
#define OFF_WCL   14155776u   // Wc lo
#define OFF_WOUT  17301504u   // Wout hi: 512*128
#define OFF_HCH   17367040u   // h_coupled hi: 3 x 128*512
#define OFF_HCL   17563648u   // h_coupled lo
#define OFF_HBH   17760256u   // h buf hi: 3 layers x 2 parity x 128*512
#define OFF_HBL   18153472u   // h buf lo
#define OFF_SCR   18546688u   // scratch (Wout lo, unused): 65536
#define USH_BYTES 37224448u   // 18612224 ushorts * 2
// ---- fp32 region (float element offsets from USH_BYTES) ----
#define FOFF_C     0u         // c state: 3 x 128*512
#define FOFF_CTERM 196608u    // Cterm: 3 x 128*2048

__device__ inline float sig_(float x)  { return 1.0f / (1.0f + __expf(-x)); }
__device__ inline float tanh_(float x) { return 2.0f / (1.0f + __expf(-2.0f * x)) - 1.0f; }

__device__ inline ushort_t f2b(float f) {
    __hip_bfloat16 h = __float2bfloat16(f);           // RNE
    return __builtin_bit_cast(unsigned short, h);
}
__device__ inline float b2f(ushort_t u) {
    unsigned int v = ((unsigned int)u) << 16;
    return __builtin_bit_cast(float, v);
}

// ---------------------------------------------------------------------------
// Weight swizzle + hi/lo split (round-2 verified).
// ---------------------------------------------------------------------------
__global__ void swz_kernel(const float* __restrict__ src,
                           ushort_t* __restrict__ dhi, ushort_t* __restrict__ dlo,
                           int K, int N) {
    int tid = blockIdx.x * 256 + threadIdx.x;
    int total = (K >> 5) * (N >> 4) * 64;
    if (tid >= total) return;
    int lane = tid & 63;
    int rest = tid >> 6;
    int NF = N >> 4;
    int nf = rest % NF;
    int kb = rest / NF;
    int kbase = kb * 32 + (lane >> 4) * 8;
    int n = nf * 16 + (lane & 15);
    union { ushort_t u[8]; uint4 v; } thi, tlo;
#pragma unroll
    for (int j = 0; j < 8; ++j) {
        float v = src[(size_t)(kbase + j) * N + n];
        ushort_t hi = f2b(v);
        thi.u[j] = hi;
        tlo.u[j] = f2b(v - b2f(hi));
    }
    *(uint4*)(dhi + (size_t)tid * 8) = thi.v;
    *(uint4*)(dlo + (size_t)tid * 8) = tlo.v;
}

__global__ void cvt_kernel(const float* __restrict__ src,
                           ushort_t* __restrict__ dhi, ushort_t* __restrict__ dlo, int n) {
    int i = blockIdx.x * 256 + threadIdx.x;
    if (i >= n) return;
    float v = src[i];
    ushort_t hi = f2b(v);
    dhi[i] = hi;
    dlo[i] = f2b(v - b2f(hi));
}

// ---------------------------------------------------------------------------
// Split-precision [16x64]-per-wave GEMM (round-2 verified) for cterm only.
// ---------------------------------------------------------------------------
__device__ inline void mfma_seg3(const ushort_t* __restrict__ Ah,
                                 const ushort_t* __restrict__ Al,
                                 const ushort_t* __restrict__ Bh,
                                 const ushort_t* __restrict__ Bl,
                                 int rowA, int cg, int nkb, frag_cd acc[4]) {
    int lane = threadIdx.x & 63;
    int koff = (lane >> 4) * 8;
#pragma unroll 2
    for (int kb = 0; kb < nkb; ++kb) {
        frag_ab ah = *(const frag_ab*)(Ah + (size_t)rowA * H_ + kb * 32 + koff);
        frag_ab al = *(const frag_ab*)(Al + (size_t)rowA * H_ + kb * 32 + koff);
#pragma unroll
        for (int q = 0; q < 4; ++q) {
            size_t bo = ((size_t)(kb * 128 + q * 32 + cg) * 64 + lane) * 8;
            frag_ab bh = *(const frag_ab*)(Bh + bo);
            frag_ab bl = *(const frag_ab*)(Bl + bo);
            acc[q] = __builtin_amdgcn_mfma_f32_16x16x32_bf16(ah, bh, acc[q], 0, 0, 0);
            acc[q] = __builtin_amdgcn_mfma_f32_16x16x32_bf16(ah, bl, acc[q], 0, 0, 0);
            acc[q] = __builtin_amdgcn_mfma_f32_16x16x32_bf16(al, bh, acc[q], 0, 0, 0);
        }
    }
}

__global__ __launch_bounds__(256) void cterm_kernel(char* __restrict__ ws,
                                                    const float* __restrict__ bias) {
    ushort_t* wsU = (ushort_t*)ws;
    float* wsF = (float*)(ws + USH_BYTES);
    int lane = threadIdx.x & 63, w = threadIdx.x >> 6;
    int bid = blockIdx.x;
    int layer = bid >> 6;
    int sub = bid & 63;
    int rg = sub >> 5, cg = sub & 31;
    int m = lane & 15, kq = lane >> 4;
    int r0 = rg * 64 + w * 16;
    int rowA = r0 + m;
    frag_cd acc[4] = {};
    mfma_seg3(wsU + OFF_HCH + layer * 65536, wsU + OFF_HCL + layer * 65536,
              wsU + OFF_WCH + (size_t)layer * 1048576, wsU + OFF_WCL + (size_t)layer * 1048576,
              rowA, cg, 16, acc);
    float* ct = wsF + FOFF_CTERM + (size_t)layer * 262144;
#pragma unroll
    for (int reg = 0; reg < 4; ++reg) {
        int row = r0 + kq * 4 + reg;
#pragma unroll
        for (int q = 0; q < 4; ++q) {
            int gcol = q * 512 + cg * 16 + m;
            ct[(size_t)row * G_ + gcol] = acc[q][reg] + bias[layer * G_ + gcol];
        }
    }
}

// ---------------------------------------------------------------------------
// Split-precision [64 rows x 64 gcols]-per-wave K-chunk segment: 4 rowtiles,
// B frags reused 4x from registers, kb in [kb0, kb0+nkb). Static acc indices.
// ---------------------------------------------------------------------------
__device__ inline void seg_accum64k(const ushort_t* __restrict__ Ah,
                                    const ushort_t* __restrict__ Al,
                                    const ushort_t* __restrict__ Bh,
                                    const ushort_t* __restrict__ Bl,
                                    int r0, int cg, int kb0, int nkb, frag_cd acc[4][4]) {
    int lane = threadIdx.x & 63;
    int m = lane & 15;
    int koff = (lane >> 4) * 8;
#pragma unroll 2
    for (int kb = kb0; kb < kb0 + nkb; ++kb) {
        frag_ab ah[4], al[4];
#pragma unroll
        for (int rt = 0; rt < 4; ++rt) {
            size_t ao = (size_t)(r0 + rt * 16 + m) * H_ + kb * 32 + koff;
            ah[rt] = *(const frag_ab*)(Ah + ao);
            al[rt] = *(const frag_ab*)(Al + ao);
        }
#pragma unroll
        for (int q = 0; q < 4; ++q) {
            size_t bo = ((size_t)(kb * 128 + q * 32 + cg) * 64 + lane) * 8;
            frag_ab bh = *(const frag_ab*)(Bh + bo);
            frag_ab bl = *(const frag_ab*)(Bl + bo);
#pragma unroll
            for (int rt = 0; rt < 4; ++rt) {
                acc[rt][q] = __builtin_amdgcn_mfma_f32_16x16x32_bf16(ah[rt], bh, acc[rt][q], 0, 0, 0);
                acc[rt][q] = __builtin_amdgcn_mfma_f32_16x16x32_bf16(ah[rt], bl, acc[rt][q], 0, 0, 0);
                acc[rt][q] = __builtin_amdgcn_mfma_f32_16x16x32_bf16(al[rt], bh, acc[rt][q], 0, 0, 0);
            }
        }
    }
}

// ---------------------------------------------------------------------------
// One pipeline tick: 194 blocks x 256 threads.
// bid < 192: cell blocks, bid = rg64*96 + (layer*32 + cg). Block computes the
//   [64r x 64gc] tile: 4 waves = K quarters, LDS partial-sum + epilogue.
// bid 192/193: out-proj, 4 waves each = (rowgroup, col-half) as in r5.
// ---------------------------------------------------------------------------
__global__ __launch_bounds__(256) void tick_kernel(const float* __restrict__ noise,
                                                   char* __restrict__ ws,
                                                   float* __restrict__ out,
                                                   const float* __restrict__ bout,
                                                   int tick) {
    __shared__ float ex[4][4096];   // 64 KB: per-wave [64r x 64gc] partials

    ushort_t* wsU = (ushort_t*)ws;
    float* wsF = (float*)(ws + USH_BYTES);
    int lane = threadIdx.x & 63;
    int w = threadIdx.x >> 6;       // wave id 0..3 (= K quarter for cells)
    int bid = blockIdx.x;
    int m = lane & 15, kq = lane >> 4;
    int koff = kq * 8;

    if (bid < 192) {
        int rg64 = bid / 96;        // 0..1: 64-row group
        int u = bid % 96;           // XCD = u % 8 (both rowgroups same XCD)
        int layer = u >> 5;
        int cg = u & 31;
        int s = tick - layer;
        if (s < 0 || s >= T_) return;
        int r0 = rg64 * 64;
        frag_cd acc[4][4] = {};

        // ---- x-path K-quarter (layer0: noise K=128 -> kb = w; else kb = w*4..+4)
        if (layer == 0) {
            const ushort_t* Bh = wsU + OFF_WXH;
            const ushort_t* Bl = wsU + OFF_WXL;
            int kb = w;
            frag_ab ah[4], al[4];
#pragma unroll
            for (int rt = 0; rt < 4; ++rt) {
                const float* np = noise +
                    ((size_t)(r0 + rt * 16 + m) * T_ + s) * ND_ + kb * 32 + koff;
                float4 f0 = *(const float4*)np;
                float4 f1 = *(const float4*)(np + 4);
                float xf[8] = {f0.x, f0.y, f0.z, f0.w, f1.x, f1.y, f1.z, f1.w};
#pragma unroll
                for (int j = 0; j < 8; ++j) {
                    ushort_t hi = f2b(xf[j]);
                    ah[rt][j] = (short)hi;
                    al[rt][j] = (short)f2b(xf[j] - b2f(hi));
                }
            }
#pragma unroll
            for (int q = 0; q < 4; ++q) {
                size_t bo = ((size_t)(kb * 128 + q * 32 + cg) * 64 + lane) * 8;
                frag_ab bh = *(const frag_ab*)(Bh + bo);
                frag_ab bl = *(const frag_ab*)(Bl + bo);
#pragma unroll
                for (int rt = 0; rt < 4; ++rt) {
                    acc[rt][q] = __builtin_amdgcn_mfma_f32_16x16x32_bf16(ah[rt], bh, acc[rt][q], 0, 0, 0);
                    acc[rt][q] = __builtin_amdgcn_mfma_f32_16x16x32_bf16(ah[rt], bl, acc[rt][q], 0, 0, 0);
                    acc[rt][q] = __builtin_amdgcn_mfma_f32_16x16x32_bf16(al[rt], bh, acc[rt][q], 0, 0, 0);
                }
            }
        } else {
            unsigned hb = (unsigned)((layer - 1) * 2 + (s & 1)) * 65536u;
            seg_accum64k(wsU + OFF_HBH + hb, wsU + OFF_HBL + hb,
                         wsU + OFF_WXH + 262144u + (size_t)(layer - 1) * 1048576,
                         wsU + OFF_WXL + 262144u + (size_t)(layer - 1) * 1048576,
                         r0, cg, w * 4, 4, acc);
        }
        // ---- h-path K-quarter (skip at s==0)
        if (s > 0) {
            unsigned hb = (unsigned)(layer * 2 + ((s - 1) & 1)) * 65536u;
            seg_accum64k(wsU + OFF_HBH + hb, wsU + OFF_HBL + hb,
                         wsU + OFF_WHH + (size_t)layer * 1048576,
                         wsU + OFF_WHL + (size_t)layer * 1048576,
                         r0, cg, w * 4, 4, acc);
        }

        // ---- write this wave's partial tile to LDS (static acc indices)
        {
            float* eb = &ex[w][0];
#pragma unroll
            for (int rt = 0; rt < 4; ++rt)
#pragma unroll
                for (int q = 0; q < 4; ++q)
#pragma unroll
                    for (int reg = 0; reg < 4; ++reg)
                        eb[(rt * 16 + kq * 4 + reg) * 64 + q * 16 + m] = acc[rt][q][reg];
        }
        __syncthreads();

        // ---- combine K-quarters + activation epilogue: 4 elements/thread
        const float* ct = wsF + FOFF_CTERM + (size_t)layer * 262144;
        float* cst = wsF + FOFF_C + layer * 65536;
        ushort_t* hhi = wsU + OFF_HBH + (layer * 2 + (s & 1)) * 65536;
        ushort_t* hlo = wsU + OFF_HBL + (layer * 2 + (s & 1)) * 65536;
        int tid = threadIdx.x;
#pragma unroll
        for (int ee = 0; ee < 4; ++ee) {
            int e = tid + ee * 256;     // 0..1023
            int row = e >> 4;           // 0..63 within tile
            int hcol = e & 15;
            int grow = r0 + row;
            int hc = cg * 16 + hcol;
            int rb = row * 64 + hcol;
            float gi = ex[0][rb +  0] + ex[1][rb +  0] + ex[2][rb +  0] + ex[3][rb +  0];
            float gf = ex[0][rb + 16] + ex[1][rb + 16] + ex[2][rb + 16] + ex[3][rb + 16];
            float gg = ex[0][rb + 32] + ex[1][rb + 32] + ex[2][rb + 32] + ex[3][rb + 32];
            float go = ex[0][rb + 48] + ex[1][rb + 48] + ex[2][rb + 48] + ex[3][rb + 48];
            const float* cr = ct + (size_t)grow * G_ + hc;
            gi += cr[0]; gf += cr[512]; gg += cr[1024]; go += cr[1536];
            float cp = (s > 0) ? cst[grow * H_ + hc] : 0.0f;
            float cn = sig_(gf) * cp + sig_(gi) * tanh_(gg);
            float hn = sig_(go) * tanh_(cn);
            cst[grow * H_ + hc] = cn;
            ushort_t hi = f2b(hn);
            hhi[grow * H_ + hc] = hi;
            hlo[grow * H_ + hc] = f2b(hn - b2f(hi));
            if (s == T_ - 1)   // h_fin, fp32, no bf16 quantization
                out[8388608u + (size_t)layer * 65536 + grow * H_ + hc] = hn;
        }
    } else {
        // ---- output projection: out[:, sp, :] = sigmoid(h2[sp] @ Wout + bout)
        int sp = tick - 3;
        if (sp < 0 || sp >= T_) return;
        int owid = (bid - 192) * 4 + w;  // 0..7
        int rg = owid >> 1;              // 4 rowgroups of 32
        int ch = owid & 1;               // 2 col halves of 64
        int r0o = rg * 32;
        const ushort_t* A  = wsU + OFF_HBH + (4 + (sp & 1)) * 65536;
        const ushort_t* Bw = wsU + OFF_WOUT;
        frag_cd acc[2][4] = {};
#pragma unroll 2
        for (int kb = 0; kb < 16; ++kb) {
            frag_ab a[2];
#pragma unroll
            for (int rt = 0; rt < 2; ++rt)
                a[rt] = *(const frag_ab*)(A + (size_t)(r0o + rt * 16 + m) * H_ + kb * 32 + koff);
#pragma unroll
            for (int cf = 0; cf < 4; ++cf) {
                frag_ab b = *(const frag_ab*)(Bw + ((size_t)(kb * 8 + ch * 4 + cf) * 64 + lane) * 8);
#pragma unroll
                for (int rt = 0; rt < 2; ++rt)
                    acc[rt][cf] = __builtin_amdgcn_mfma_f32_16x16x32_bf16(a[rt], b, acc[rt][cf], 0, 0, 0);
            }
        }
#pragma unroll
        for (int rt = 0; rt < 2; ++rt)
#pragma unroll
            for (int cf = 0; cf < 4; ++cf)
#pragma unroll
                for (int reg = 0; reg < 4; ++reg) {
                    int row = r0o + rt * 16 + kq * 4 + reg;
                    int oc = ch * 64 + cf * 16 + m;
                    out[((size_t)row * T_ + sp) * LD_ + oc] =
                        sig_(acc[rt][cf][reg] + bout[oc]);
                }
    }
}

extern "C" void kernel_launch(void* const* d_in, const int* in_sizes, int n_in,
                              void* d_out, int out_size, void* d_ws, size_t ws_size,
                              hipStream_t stream) {
    const float* noise = (const float*)d_in[0];
    const float* hcpl  = (const float*)d_in[1];
    const float* Wx0   = (const float*)d_in[2];
    const float* Wxr   = (const float*)d_in[3];
    const float* Wh    = (const float*)d_in[4];
    const float* Wc    = (const float*)d_in[5];
    const float* bias  = (const float*)d_in[6];
    const float* Wout  = (const float*)d_in[7];
    const float* bout  = (const float*)d_in[8];
    float* out = (float*)d_out;
    char* ws = (char*)d_ws;
    ushort_t* wsU = (ushort_t*)ws;

    auto launch_swz = [&](const float* src, unsigned ohi, unsigned olo, int K, int N) {
        int total = (K / 32) * (N / 16) * 64;
        swz_kernel<<<(total + 255) / 256, 256, 0, stream>>>(src, wsU + ohi, wsU + olo, K, N);
    };
    for (int l = 0; l < 3; ++l)
        launch_swz(Wh + (size_t)l * H_ * G_, OFF_WHH + l * 1048576u, OFF_WHL + l * 1048576u, H_, G_);
    launch_swz(Wx0, OFF_WXH, OFF_WXL, ND_, G_);
    for (int l = 0; l < 2; ++l)
        launch_swz(Wxr + (size_t)l * H_ * G_, OFF_WXH + 262144u + l * 1048576u,
                   OFF_WXL + 262144u + l * 1048576u, H_, G_);
    for (int l = 0; l < 3; ++l)
        launch_swz(Wc + (size_t)l * H_ * G_, OFF_WCH + l * 1048576u, OFF_WCL + l * 1048576u, H_, G_);
    launch_swz(Wout, OFF_WOUT, OFF_SCR, H_, LD_);
    cvt_kernel<<<(3 * B_ * H_ + 255) / 256, 256, 0, stream>>>(hcpl, wsU + OFF_HCH, wsU + OFF_HCL,
                                                              3 * B_ * H_);
    cterm_kernel<<<192, 256, 0, stream>>>(ws, bias);

    // 515 ticks: layer l covers steps at ticks [l, l+511]; out-proj at [3, 514]
    for (int t = 0; t < 515; ++t)
        tick_kernel<<<194, 256, 0, stream>>>(noise, ws, out, bout, t);
}